// Round 1
// baseline (2905.136 us; speedup 1.0000x reference)
//
#include <hip/hip_runtime.h>

// EdgeNorm: per-destination-node mean/std normalization of edge scores, then
// per-head gain/bias.  E=3.2M edges, H=8 heads, N=100k nodes (avg degree 32).
//
// Structure:
//   1. edge_stats:  atomicAdd per-(node,head) sum and sumsq, per-node count.
//   2. node_coeff:  A = gain*inv_std, B = bias - A*mean  (in-place over ws).
//   3. edge_out:    out[e,h] = A[dst,h]*x + B[dst,h]     (pure gather+FMA).

#define NHEADS 8

__global__ void edge_stats_kernel(const float* __restrict__ scores,
                                  const int* __restrict__ dst,
                                  float* __restrict__ sums,
                                  float* __restrict__ sumsq,
                                  int* __restrict__ counts,
                                  int num_edges) {
    int e = blockIdx.x * blockDim.x + threadIdx.x;
    if (e >= num_edges) return;
    int d = dst[e];
    const float4* p = reinterpret_cast<const float4*>(scores + (size_t)e * NHEADS);
    float4 x0 = p[0];
    float4 x1 = p[1];
    float* s = sums  + (size_t)d * NHEADS;
    float* q = sumsq + (size_t)d * NHEADS;
    atomicAdd(s + 0, x0.x);
    atomicAdd(s + 1, x0.y);
    atomicAdd(s + 2, x0.z);
    atomicAdd(s + 3, x0.w);
    atomicAdd(s + 4, x1.x);
    atomicAdd(s + 5, x1.y);
    atomicAdd(s + 6, x1.z);
    atomicAdd(s + 7, x1.w);
    atomicAdd(q + 0, x0.x * x0.x);
    atomicAdd(q + 1, x0.y * x0.y);
    atomicAdd(q + 2, x0.z * x0.z);
    atomicAdd(q + 3, x0.w * x0.w);
    atomicAdd(q + 4, x1.x * x1.x);
    atomicAdd(q + 5, x1.y * x1.y);
    atomicAdd(q + 6, x1.z * x1.z);
    atomicAdd(q + 7, x1.w * x1.w);
    atomicAdd(counts + d, 1);
}

// One thread per (node, head).  Reads sums/sumsq/counts, writes A into sums
// and B into sumsq (in-place: each thread touches only its own element).
__global__ void node_coeff_kernel(float* __restrict__ sums,
                                  float* __restrict__ sumsq,
                                  const int* __restrict__ counts,
                                  const float* __restrict__ gain,
                                  const float* __restrict__ bias,
                                  int total) {
    int i = blockIdx.x * blockDim.x + threadIdx.x;
    if (i >= total) return;
    int h = i & (NHEADS - 1);
    int node = i >> 3;
    float c = (float)counts[node];
    float cm = fmaxf(c, 1.0f);           // ref: means = sums / max(counts,1)
    float s = sums[i];
    float mean = s / cm;
    // var_sum = sum(x^2) - sum(x)^2/c ; clamp tiny negative from rounding.
    float var_sum = fmaxf(sumsq[i] - s * mean, 0.0f);
    // ref divides by raw counts (NaN at degree-0 nodes, never gathered);
    // using cm avoids NaN and degree-0 nodes are never read back.
    float stdev = sqrtf(var_sum / cm);
    float inv = 1.0f / fmaxf(stdev, 1e-5f);
    float g = gain[h];
    float A = g * inv;
    float B = fmaf(-A, mean, bias[h]);
    sums[i]  = A;
    sumsq[i] = B;
}

__global__ void edge_out_kernel(const float* __restrict__ scores,
                                const int* __restrict__ dst,
                                const float* __restrict__ A,
                                const float* __restrict__ B,
                                float* __restrict__ out,
                                int num_edges) {
    int e = blockIdx.x * blockDim.x + threadIdx.x;
    if (e >= num_edges) return;
    int d = dst[e];
    const float4* px = reinterpret_cast<const float4*>(scores + (size_t)e * NHEADS);
    const float4* pa = reinterpret_cast<const float4*>(A + (size_t)d * NHEADS);
    const float4* pb = reinterpret_cast<const float4*>(B + (size_t)d * NHEADS);
    float4 x0 = px[0], x1 = px[1];
    float4 a0 = pa[0], a1 = pa[1];
    float4 b0 = pb[0], b1 = pb[1];
    float4 o0, o1;
    o0.x = fmaf(a0.x, x0.x, b0.x);
    o0.y = fmaf(a0.y, x0.y, b0.y);
    o0.z = fmaf(a0.z, x0.z, b0.z);
    o0.w = fmaf(a0.w, x0.w, b0.w);
    o1.x = fmaf(a1.x, x1.x, b1.x);
    o1.y = fmaf(a1.y, x1.y, b1.y);
    o1.z = fmaf(a1.z, x1.z, b1.z);
    o1.w = fmaf(a1.w, x1.w, b1.w);
    float4* po = reinterpret_cast<float4*>(out + (size_t)e * NHEADS);
    po[0] = o0;
    po[1] = o1;
}

extern "C" void kernel_launch(void* const* d_in, const int* in_sizes, int n_in,
                              void* d_out, int out_size, void* d_ws, size_t ws_size,
                              hipStream_t stream) {
    // Inputs (setup_inputs order): edge_scores, gain, bias, dst, num_nodes
    const float* scores = (const float*)d_in[0];
    const float* gain   = (const float*)d_in[1];
    const float* bias   = (const float*)d_in[2];
    const int*   dst    = (const int*)d_in[3];

    const int E = in_sizes[3];          // 3.2M
    const int N = 100000;               // reference NUM_NODES (device scalar; fixed by problem)
    const int NH = N * NHEADS;

    // Workspace layout: [ sums: NH f32 | sumsq: NH f32 | counts: N i32 ]  (~6.8 MB)
    float* sums   = (float*)d_ws;
    float* sumsq  = sums + NH;
    int*   counts = (int*)(sumsq + NH);

    hipMemsetAsync(d_ws, 0, (size_t)(2 * NH) * sizeof(float) + (size_t)N * sizeof(int),
                   stream);

    const int B = 256;
    int blocks_e = (E + B - 1) / B;
    edge_stats_kernel<<<blocks_e, B, 0, stream>>>(scores, dst, sums, sumsq, counts, E);
    node_coeff_kernel<<<(NH + B - 1) / B, B, 0, stream>>>(sums, sumsq, counts, gain, bias, NH);
    edge_out_kernel<<<blocks_e, B, 0, stream>>>(scores, dst, sums, sumsq, (float*)d_out, E);
}

// Round 2
// 989.629 us; speedup vs baseline: 2.9356x; 2.9356x over previous
//
#include <hip/hip_runtime.h>

// EdgeNorm, round 2: atomic-free segmented stats via bucketed LDS histograms.
//
// Round-1 lesson (rocprof): 54.4M agent-scope fp32 atomics = 1.74 GB of 32B
// fabric transactions at ~650 GB/s = 2685 us. Per-XCD L2s are not coherent, so
// device atomics bypass to the fabric. Fix: never issue global float atomics.
//
// Pipeline:
//   0. bucketize : u8 bucket_id[e] = dst[e]/896           (3.2 MB, L2-resident)
//   1. bucket_stats: block (part, bucket) scans its edge chunk's bucket_id
//      bytes, accumulates matching edges into a 60.9 KB LDS tile
//      (896 nodes x {8 sum, 8 sumsq, count}), stores tile to a private
//      partials slab -- plain stores, zero global atomics.
//   2. coeff     : reduce PARTS partials per (node,head); A=gain*inv_std,
//                  B=bias-A*mean.
//   3. edge_out  : out = A[dst]*x + B[dst]  (gather + FMA).

#define NHEADS 8
#define KNODES 896           // nodes per bucket; 896*17*4 = 60928 B LDS < 64 KB
#define SLOTS  17            // 8 sum + 8 sumsq + 1 count
#define NNODES 100000

__global__ __launch_bounds__(256)
void bucketize_kernel(const int* __restrict__ dst, unsigned char* __restrict__ bid,
                      int E, int Epad) {
    int i = (blockIdx.x * 256 + threadIdx.x) * 4;
    if (i >= Epad) return;
    if (i + 4 <= E) {
        int4 d = *reinterpret_cast<const int4*>(dst + i);
        uchar4 b;
        b.x = (unsigned char)((unsigned)d.x / KNODES);
        b.y = (unsigned char)((unsigned)d.y / KNODES);
        b.z = (unsigned char)((unsigned)d.z / KNODES);
        b.w = (unsigned char)((unsigned)d.w / KNODES);
        *reinterpret_cast<uchar4*>(bid + i) = b;
    } else {
        for (int j = 0; j < 4; j++)
            bid[i + j] = (i + j < E) ? (unsigned char)((unsigned)dst[i + j] / KNODES)
                                     : (unsigned char)0xFF;   // pad: matches no bucket
    }
}

__global__ __launch_bounds__(256)
void bucket_stats_kernel(const unsigned char* __restrict__ bid,
                         const int* __restrict__ dst,
                         const float* __restrict__ scores,
                         float* __restrict__ partials,
                         int E, int chunk) {
    __shared__ float st[KNODES * SLOTS];
    const int part   = blockIdx.x;
    const int parts  = gridDim.x;
    const int bucket = blockIdx.y;

    float4* stv = reinterpret_cast<float4*>(st);
    for (int i = threadIdx.x; i < (KNODES * SLOTS) / 4; i += 256)
        stv[i] = float4{0.f, 0.f, 0.f, 0.f};
    __syncthreads();

    const unsigned bcast   = (unsigned)bucket * 0x01010101u;
    const int      nodebase = bucket * KNODES;
    const int e0 = part * chunk;                 // chunk is a multiple of 16
    const int e1 = min(e0 + chunk, E);

    for (int base = e0 + (int)threadIdx.x * 16; base < e1; base += 256 * 16) {
        uint4 w = *reinterpret_cast<const uint4*>(bid + base);  // bid padded to 16
        unsigned ww[4] = {w.x, w.y, w.z, w.w};
        #pragma unroll
        for (int j = 0; j < 4; j++) {
            unsigned x = ww[j] ^ bcast;
            // exact "contains zero byte" test (Bit Twiddling Hacks); per-byte
            // bits can be borrow-polluted so re-verify each byte below.
            if ((x - 0x01010101u) & ~x & 0x80808080u) {
                #pragma unroll
                for (int b = 0; b < 4; b++) {
                    if (((x >> (8 * b)) & 0xFFu) == 0u) {
                        int e = base + j * 4 + b;
                        int k = dst[e] - nodebase;
                        const float4* p =
                            reinterpret_cast<const float4*>(scores + (size_t)e * NHEADS);
                        float4 a = p[0], c = p[1];
                        float* s = st + k * SLOTS;
                        atomicAdd(s + 0,  a.x);       atomicAdd(s + 1,  a.y);
                        atomicAdd(s + 2,  a.z);       atomicAdd(s + 3,  a.w);
                        atomicAdd(s + 4,  c.x);       atomicAdd(s + 5,  c.y);
                        atomicAdd(s + 6,  c.z);       atomicAdd(s + 7,  c.w);
                        atomicAdd(s + 8,  a.x * a.x); atomicAdd(s + 9,  a.y * a.y);
                        atomicAdd(s + 10, a.z * a.z); atomicAdd(s + 11, a.w * a.w);
                        atomicAdd(s + 12, c.x * c.x); atomicAdd(s + 13, c.y * c.y);
                        atomicAdd(s + 14, c.z * c.z); atomicAdd(s + 15, c.w * c.w);
                        atomicAdd(s + 16, 1.0f);
                    }
                }
            }
        }
    }
    __syncthreads();

    float* out = partials + ((size_t)bucket * parts + part) * (KNODES * SLOTS);
    float4* outv = reinterpret_cast<float4*>(out);
    for (int i = threadIdx.x; i < (KNODES * SLOTS) / 4; i += 256)
        outv[i] = stv[i];
}

__global__ __launch_bounds__(256)
void coeff_kernel(const float* __restrict__ partials,
                  const float* __restrict__ gain,
                  const float* __restrict__ bias,
                  float* __restrict__ A, float* __restrict__ B,
                  int parts, int total) {
    int i = blockIdx.x * 256 + threadIdx.x;
    if (i >= total) return;
    int node = i >> 3, h = i & 7;
    int bucket = (int)((unsigned)node / KNODES);
    int k = node - bucket * KNODES;
    const float* base =
        partials + (size_t)bucket * parts * (KNODES * SLOTS) + (size_t)k * SLOTS;
    float s = 0.f, q = 0.f, c = 0.f;
    for (int p = 0; p < parts; p++) {
        const float* pp = base + (size_t)p * (KNODES * SLOTS);
        s += pp[h];
        q += pp[8 + h];
        c += pp[16];
    }
    float cm   = fmaxf(c, 1.0f);                 // ref: sums / max(counts,1)
    float mean = s / cm;
    float var  = fmaxf(q - s * mean, 0.0f);      // one-pass variance, clamped
    float inv  = 1.0f / fmaxf(sqrtf(var / cm), 1e-5f);
    float a = gain[h] * inv;
    A[i] = a;
    B[i] = fmaf(-a, mean, bias[h]);
}

__global__ __launch_bounds__(256)
void edge_out_kernel(const float* __restrict__ scores,
                     const int* __restrict__ dst,
                     const float* __restrict__ A,
                     const float* __restrict__ B,
                     float* __restrict__ out,
                     int num_edges) {
    int e = blockIdx.x * 256 + threadIdx.x;
    if (e >= num_edges) return;
    int d = dst[e];
    const float4* px = reinterpret_cast<const float4*>(scores + (size_t)e * NHEADS);
    const float4* pa = reinterpret_cast<const float4*>(A + (size_t)d * NHEADS);
    const float4* pb = reinterpret_cast<const float4*>(B + (size_t)d * NHEADS);
    float4 x0 = px[0], x1 = px[1];
    float4 a0 = pa[0], a1 = pa[1];
    float4 b0 = pb[0], b1 = pb[1];
    float4 o0, o1;
    o0.x = fmaf(a0.x, x0.x, b0.x);
    o0.y = fmaf(a0.y, x0.y, b0.y);
    o0.z = fmaf(a0.z, x0.z, b0.z);
    o0.w = fmaf(a0.w, x0.w, b0.w);
    o1.x = fmaf(a1.x, x1.x, b1.x);
    o1.y = fmaf(a1.y, x1.y, b1.y);
    o1.z = fmaf(a1.z, x1.z, b1.z);
    o1.w = fmaf(a1.w, x1.w, b1.w);
    float4* po = reinterpret_cast<float4*>(out + (size_t)e * NHEADS);
    po[0] = o0;
    po[1] = o1;
}

// ---- round-1 fallback (global atomics) in case ws_size is too small --------
__global__ void edge_stats_fallback(const float* __restrict__ scores,
                                    const int* __restrict__ dst,
                                    float* __restrict__ sums,
                                    float* __restrict__ sumsq,
                                    int* __restrict__ counts,
                                    int num_edges) {
    int e = blockIdx.x * blockDim.x + threadIdx.x;
    if (e >= num_edges) return;
    int d = dst[e];
    const float4* p = reinterpret_cast<const float4*>(scores + (size_t)e * NHEADS);
    float4 x0 = p[0], x1 = p[1];
    float* s = sums  + (size_t)d * NHEADS;
    float* q = sumsq + (size_t)d * NHEADS;
    atomicAdd(s + 0, x0.x); atomicAdd(s + 1, x0.y);
    atomicAdd(s + 2, x0.z); atomicAdd(s + 3, x0.w);
    atomicAdd(s + 4, x1.x); atomicAdd(s + 5, x1.y);
    atomicAdd(s + 6, x1.z); atomicAdd(s + 7, x1.w);
    atomicAdd(q + 0, x0.x * x0.x); atomicAdd(q + 1, x0.y * x0.y);
    atomicAdd(q + 2, x0.z * x0.z); atomicAdd(q + 3, x0.w * x0.w);
    atomicAdd(q + 4, x1.x * x1.x); atomicAdd(q + 5, x1.y * x1.y);
    atomicAdd(q + 6, x1.z * x1.z); atomicAdd(q + 7, x1.w * x1.w);
    atomicAdd(counts + d, 1);
}

__global__ void coeff_fallback(float* __restrict__ sums, float* __restrict__ sumsq,
                               const int* __restrict__ counts,
                               const float* __restrict__ gain,
                               const float* __restrict__ bias, int total) {
    int i = blockIdx.x * blockDim.x + threadIdx.x;
    if (i >= total) return;
    int h = i & (NHEADS - 1);
    int node = i >> 3;
    float cm = fmaxf((float)counts[node], 1.0f);
    float s = sums[i];
    float mean = s / cm;
    float var_sum = fmaxf(sumsq[i] - s * mean, 0.0f);
    float inv = 1.0f / fmaxf(sqrtf(var_sum / cm), 1e-5f);
    float a = gain[h] * inv;
    sums[i]  = a;
    sumsq[i] = fmaf(-a, mean, bias[h]);
}
// ---------------------------------------------------------------------------

extern "C" void kernel_launch(void* const* d_in, const int* in_sizes, int n_in,
                              void* d_out, int out_size, void* d_ws, size_t ws_size,
                              hipStream_t stream) {
    const float* scores = (const float*)d_in[0];
    const float* gain   = (const float*)d_in[1];
    const float* bias   = (const float*)d_in[2];
    const int*   dst    = (const int*)d_in[3];

    const int E  = in_sizes[3];
    const int N  = NNODES;
    const int NB = (N + KNODES - 1) / KNODES;       // 112 buckets (fits u8)
    const int NH = N * NHEADS;

    size_t Epad   = ((size_t)E + 15) & ~(size_t)15;
    // ws layout: [A: NH f32 | B: NH f32 | bucket_id: Epad u8 | partials]
    float* A = (float*)d_ws;
    float* Bc = A + NH;
    unsigned char* bid = (unsigned char*)(Bc + NH);
    size_t offPart = ((size_t)NH * 8 + Epad + 255) & ~(size_t)255;
    float* partials = (float*)((char*)d_ws + offPart);

    int parts = 0;
    for (int p = 8; p >= 1; p >>= 1) {
        size_t need = offPart + (size_t)NB * p * KNODES * SLOTS * sizeof(float);
        if (need <= ws_size) { parts = p; break; }
    }

    const int B = 256;
    if (parts > 0) {
        int chunk = (((E + parts - 1) / parts) + 15) & ~15;
        bucketize_kernel<<<(int)((Epad / 4 + B - 1) / B), B, 0, stream>>>(dst, bid, E, (int)Epad);
        dim3 g1(parts, NB);
        bucket_stats_kernel<<<g1, B, 0, stream>>>(bid, dst, scores, partials, E, chunk);
        coeff_kernel<<<(NH + B - 1) / B, B, 0, stream>>>(partials, gain, bias, A, Bc, parts, NH);
        edge_out_kernel<<<(E + B - 1) / B, B, 0, stream>>>(scores, dst, A, Bc, (float*)d_out, E);
    } else {
        // ws too small for partials: round-1 atomic path
        float* sums  = (float*)d_ws;
        float* sumsq = sums + NH;
        int*   counts = (int*)(sumsq + NH);
        hipMemsetAsync(d_ws, 0, (size_t)(2 * NH) * sizeof(float) + (size_t)N * sizeof(int), stream);
        int blocks_e = (E + B - 1) / B;
        edge_stats_fallback<<<blocks_e, B, 0, stream>>>(scores, dst, sums, sumsq, counts, E);
        coeff_fallback<<<(NH + B - 1) / B, B, 0, stream>>>(sums, sumsq, counts, gain, bias, NH);
        edge_out_kernel<<<blocks_e, B, 0, stream>>>(scores, dst, sums, sumsq, (float*)d_out, E);
    }
}

// Round 3
// 829.435 us; speedup vs baseline: 3.5025x; 1.1931x over previous
//
#include <hip/hip_runtime.h>

// EdgeNorm, round 3: scan -> LDS queue compaction -> dense drain.
//
// Round-2 lesson (rocprof): bucket_stats 760us, VALUBusy 10.5%, HBM 2.7%,
// occupancy 20.6% -> latency-bound. The divergent match path (~0.9% hit rate)
// serialized its scattered dst/scores gathers (~600cyc each, ~1 in flight per
// wave). Fix: compact matching edge ids into an LDS queue during the scan,
// then drain densely so all 256 threads issue gathers in parallel. Also
// KNODES 896->512 (power of 2, LDS 51.2KB -> 3 blocks/CU vs 2).
//
// Pipeline:
//   0. bucketize : u8 bid[e] = dst[e]>>9            (3.2 MB, L2-resident)
//   1. bucket_stats: block (part,bucket) scans bid bytes; matches -> LDS
//      queue; drain densely into LDS stats tile (512 nodes x 17 slots);
//      plain stores to private partials slab. Zero global atomics.
//   2. coeff     : reduce partials; AB[node][0:8]=gain*inv_std,
//                  AB[node][8:16]=bias-A*mean  (one 64B line per node).
//   3. edge_out  : out = A[dst]*x + B[dst]  (single-line gather + FMA).

#define NHEADS 8
#define KNODES 512
#define KSHIFT 9
#define SLOTS  17            // 8 sum + 8 sumsq + 1 count
#define NNODES 100000
#define QCAP   4096          // LDS queue entries (16 KB)
#define DRAIN  1024          // drain threshold; growth/iter ~21 avg (4096/196)

__global__ __launch_bounds__(256)
void bucketize_kernel(const int* __restrict__ dst, unsigned char* __restrict__ bid,
                      int E, int Epad) {
    int i = (blockIdx.x * 256 + threadIdx.x) * 4;
    if (i >= Epad) return;
    if (i + 4 <= E) {
        int4 d = *reinterpret_cast<const int4*>(dst + i);
        uchar4 b;
        b.x = (unsigned char)((unsigned)d.x >> KSHIFT);
        b.y = (unsigned char)((unsigned)d.y >> KSHIFT);
        b.z = (unsigned char)((unsigned)d.z >> KSHIFT);
        b.w = (unsigned char)((unsigned)d.w >> KSHIFT);
        *reinterpret_cast<uchar4*>(bid + i) = b;
    } else {
        for (int j = 0; j < 4; j++)
            bid[i + j] = (i + j < E) ? (unsigned char)((unsigned)dst[i + j] >> KSHIFT)
                                     : (unsigned char)0xFF;   // pad: never matches
    }
}

__global__ __launch_bounds__(256)
void bucket_stats_kernel(const unsigned char* __restrict__ bid,
                         const int* __restrict__ dst,
                         const float* __restrict__ scores,
                         float* __restrict__ partials,
                         int E, int chunk) {
    __shared__ float st[KNODES * SLOTS];     // 34816 B
    __shared__ unsigned queue[QCAP];         // 16384 B
    __shared__ int qcount;                   // total 51204 B -> 3 blocks/CU

    const int part   = blockIdx.x;
    const int parts  = gridDim.x;
    const int bucket = blockIdx.y;

    float4* stv = reinterpret_cast<float4*>(st);
    for (int i = threadIdx.x; i < (KNODES * SLOTS) / 4; i += 256)
        stv[i] = float4{0.f, 0.f, 0.f, 0.f};
    if (threadIdx.x == 0) qcount = 0;
    __syncthreads();

    const unsigned bcast = (unsigned)bucket * 0x01010101u;
    const int e0 = part * chunk;             // chunk is a multiple of 16
    const int e1 = min(e0 + chunk, E);
    const int niter = (chunk + 256 * 16 - 1) / (256 * 16);

    for (int it = 0; it < niter; ++it) {
        int base = e0 + it * (256 * 16) + (int)threadIdx.x * 16;
        if (base < e1) {
            uint4 w = *reinterpret_cast<const uint4*>(bid + base);  // bid 16B-padded
            unsigned ww[4] = {w.x, w.y, w.z, w.w};
            #pragma unroll
            for (int j = 0; j < 4; ++j) {
                unsigned x = ww[j] ^ bcast;
                // exact "contains zero byte" test; re-verify per byte (borrow
                // pollution) below.
                if ((x - 0x01010101u) & ~x & 0x80808080u) {
                    #pragma unroll
                    for (int b = 0; b < 4; ++b) {
                        if (((x >> (8 * b)) & 0xFFu) == 0u) {
                            int slot = atomicAdd(&qcount, 1);
                            queue[slot] = (unsigned)(base + j * 4 + b);
                        }
                    }
                }
            }
        }
        __syncthreads();                     // pushes complete; qcount stable
        int n = qcount;                      // uniform across block
        if (n >= DRAIN || it == niter - 1) {
            // Dense drain: every thread owns distinct queued edges -> 256
            // scattered gathers in flight per round instead of ~1/wave.
            for (int i = (int)threadIdx.x; i < n; i += 256) {
                int e = (int)queue[i];
                int d = dst[e];
                int k = d & (KNODES - 1);
                const float4* p =
                    reinterpret_cast<const float4*>(scores + (size_t)e * NHEADS);
                float4 a = p[0], c = p[1];
                float* s = st + k * SLOTS;   // stride 17 (odd) -> conflict-free
                atomicAdd(s + 0,  a.x);       atomicAdd(s + 1,  a.y);
                atomicAdd(s + 2,  a.z);       atomicAdd(s + 3,  a.w);
                atomicAdd(s + 4,  c.x);       atomicAdd(s + 5,  c.y);
                atomicAdd(s + 6,  c.z);       atomicAdd(s + 7,  c.w);
                atomicAdd(s + 8,  a.x * a.x); atomicAdd(s + 9,  a.y * a.y);
                atomicAdd(s + 10, a.z * a.z); atomicAdd(s + 11, a.w * a.w);
                atomicAdd(s + 12, c.x * c.x); atomicAdd(s + 13, c.y * c.y);
                atomicAdd(s + 14, c.z * c.z); atomicAdd(s + 15, c.w * c.w);
                atomicAdd(s + 16, 1.0f);
            }
            __syncthreads();                 // drain done before reset
            if (threadIdx.x == 0) qcount = 0;
            __syncthreads();                 // reset visible before next pushes
        }
    }

    float* out = partials + ((size_t)bucket * parts + part) * (KNODES * SLOTS);
    float4* outv = reinterpret_cast<float4*>(out);
    for (int i = threadIdx.x; i < (KNODES * SLOTS) / 4; i += 256)
        outv[i] = stv[i];
}

// AB layout: per node 16 floats = one 64B line: [A(8) | B(8)].
__global__ __launch_bounds__(256)
void coeff_kernel(const float* __restrict__ partials,
                  const float* __restrict__ gain,
                  const float* __restrict__ bias,
                  float* __restrict__ AB,
                  int parts, int total) {
    int i = blockIdx.x * 256 + threadIdx.x;
    if (i >= total) return;
    int node = i >> 3, h = i & 7;
    int bucket = node >> KSHIFT;
    int k = node & (KNODES - 1);
    const float* base =
        partials + (size_t)bucket * parts * (KNODES * SLOTS) + (size_t)k * SLOTS;
    float s = 0.f, q = 0.f, c = 0.f;
    for (int p = 0; p < parts; p++) {
        const float* pp = base + (size_t)p * (KNODES * SLOTS);
        s += pp[h];
        q += pp[8 + h];
        c += pp[16];
    }
    float cm   = fmaxf(c, 1.0f);                 // ref: sums / max(counts,1)
    float mean = s / cm;
    float var  = fmaxf(q - s * mean, 0.0f);      // one-pass variance, clamped
    float inv  = 1.0f / fmaxf(sqrtf(var / cm), 1e-5f);
    float a = gain[h] * inv;
    AB[(size_t)node * 16 + h]     = a;
    AB[(size_t)node * 16 + 8 + h] = fmaf(-a, mean, bias[h]);
}

__global__ __launch_bounds__(256)
void edge_out_kernel(const float* __restrict__ scores,
                     const int* __restrict__ dst,
                     const float* __restrict__ AB,
                     float* __restrict__ out,
                     int num_edges) {
    int e = blockIdx.x * 256 + threadIdx.x;
    if (e >= num_edges) return;
    int d = dst[e];
    const float4* px = reinterpret_cast<const float4*>(scores + (size_t)e * NHEADS);
    const float4* pab = reinterpret_cast<const float4*>(AB + (size_t)d * 16);
    float4 x0 = px[0], x1 = px[1];
    float4 a0 = pab[0], a1 = pab[1];
    float4 b0 = pab[2], b1 = pab[3];
    float4 o0, o1;
    o0.x = fmaf(a0.x, x0.x, b0.x);
    o0.y = fmaf(a0.y, x0.y, b0.y);
    o0.z = fmaf(a0.z, x0.z, b0.z);
    o0.w = fmaf(a0.w, x0.w, b0.w);
    o1.x = fmaf(a1.x, x1.x, b1.x);
    o1.y = fmaf(a1.y, x1.y, b1.y);
    o1.z = fmaf(a1.z, x1.z, b1.z);
    o1.w = fmaf(a1.w, x1.w, b1.w);
    float4* po = reinterpret_cast<float4*>(out + (size_t)e * NHEADS);
    po[0] = o0;
    po[1] = o1;
}

// ---- global-atomic fallback (only if ws too small for partials) -----------
__global__ void edge_stats_fallback(const float* __restrict__ scores,
                                    const int* __restrict__ dst,
                                    float* __restrict__ sums,
                                    float* __restrict__ sumsq,
                                    int* __restrict__ counts,
                                    int num_edges) {
    int e = blockIdx.x * blockDim.x + threadIdx.x;
    if (e >= num_edges) return;
    int d = dst[e];
    const float4* p = reinterpret_cast<const float4*>(scores + (size_t)e * NHEADS);
    float4 x0 = p[0], x1 = p[1];
    float* s = sums  + (size_t)d * NHEADS;
    float* q = sumsq + (size_t)d * NHEADS;
    atomicAdd(s + 0, x0.x); atomicAdd(s + 1, x0.y);
    atomicAdd(s + 2, x0.z); atomicAdd(s + 3, x0.w);
    atomicAdd(s + 4, x1.x); atomicAdd(s + 5, x1.y);
    atomicAdd(s + 6, x1.z); atomicAdd(s + 7, x1.w);
    atomicAdd(q + 0, x0.x * x0.x); atomicAdd(q + 1, x0.y * x0.y);
    atomicAdd(q + 2, x0.z * x0.z); atomicAdd(q + 3, x0.w * x0.w);
    atomicAdd(q + 4, x1.x * x1.x); atomicAdd(q + 5, x1.y * x1.y);
    atomicAdd(q + 6, x1.z * x1.z); atomicAdd(q + 7, x1.w * x1.w);
    atomicAdd(counts + d, 1);
}

__global__ void coeff_fallback(const float* __restrict__ sums,
                               const float* __restrict__ sumsq,
                               const int* __restrict__ counts,
                               const float* __restrict__ gain,
                               const float* __restrict__ bias,
                               float* __restrict__ AB, int total) {
    int i = blockIdx.x * blockDim.x + threadIdx.x;
    if (i >= total) return;
    int h = i & (NHEADS - 1);
    int node = i >> 3;
    float cm = fmaxf((float)counts[node], 1.0f);
    float s = sums[i];
    float mean = s / cm;
    float var_sum = fmaxf(sumsq[i] - s * mean, 0.0f);
    float inv = 1.0f / fmaxf(sqrtf(var_sum / cm), 1e-5f);
    float a = gain[h] * inv;
    AB[(size_t)node * 16 + h]     = a;
    AB[(size_t)node * 16 + 8 + h] = fmaf(-a, mean, bias[h]);
}
// ---------------------------------------------------------------------------

extern "C" void kernel_launch(void* const* d_in, const int* in_sizes, int n_in,
                              void* d_out, int out_size, void* d_ws, size_t ws_size,
                              hipStream_t stream) {
    const float* scores = (const float*)d_in[0];
    const float* gain   = (const float*)d_in[1];
    const float* bias   = (const float*)d_in[2];
    const int*   dst    = (const int*)d_in[3];

    const int E  = in_sizes[3];
    const int N  = NNODES;
    const int NB = (N + KNODES - 1) / KNODES;       // 196 buckets (fits u8)
    const int NH = N * NHEADS;

    size_t Epad = ((size_t)E + 15) & ~(size_t)15;
    // ws layout: [AB: N*16 f32 (6.4MB) | bid: Epad u8 | partials]
    float* AB = (float*)d_ws;
    unsigned char* bid = (unsigned char*)(AB + (size_t)N * 16);
    size_t offPart = ((size_t)N * 16 * 4 + Epad + 255) & ~(size_t)255;
    float* partials = (float*)((char*)d_ws + offPart);

    int parts = 0;
    for (int p = 8; p >= 1; p >>= 1) {
        size_t need = offPart + (size_t)NB * p * KNODES * SLOTS * sizeof(float);
        if (need <= ws_size) { parts = p; break; }
    }

    const int B = 256;
    if (parts > 0) {
        int chunk = (((E + parts - 1) / parts) + 15) & ~15;
        bucketize_kernel<<<(int)((Epad / 4 + B - 1) / B), B, 0, stream>>>(dst, bid, E, (int)Epad);
        dim3 g1(parts, NB);
        bucket_stats_kernel<<<g1, B, 0, stream>>>(bid, dst, scores, partials, E, chunk);
        coeff_kernel<<<(NH + B - 1) / B, B, 0, stream>>>(partials, gain, bias, AB, parts, NH);
        edge_out_kernel<<<(E + B - 1) / B, B, 0, stream>>>(scores, dst, AB, (float*)d_out, E);
    } else {
        // ws too small: global-atomic path
        float* sums  = (float*)((char*)d_ws + (size_t)N * 16 * 4);
        float* sumsq = sums + NH;
        int*   counts = (int*)(sumsq + NH);
        hipMemsetAsync(sums, 0, (size_t)(2 * NH) * sizeof(float) + (size_t)N * sizeof(int), stream);
        int blocks_e = (E + B - 1) / B;
        edge_stats_fallback<<<blocks_e, B, 0, stream>>>(scores, dst, sums, sumsq, counts, E);
        coeff_fallback<<<(NH + B - 1) / B, B, 0, stream>>>(sums, sumsq, counts, gain, bias, AB, NH);
        edge_out_kernel<<<blocks_e, B, 0, stream>>>(scores, dst, AB, (float*)d_out, E);
    }
}

// Round 4
// 601.985 us; speedup vs baseline: 4.8259x; 1.3778x over previous
//
#include <hip/hip_runtime.h>

// EdgeNorm, round 4: counting-sort scatter -> dense per-bucket stats.
//
// Round-3 lesson (rocprof): the bucketed scan re-read 627 MB of bucket-id
// bytes (196x redundancy) under a per-4KB __syncthreads, ~7.5k cyc per block
// iteration, VALUBusy 11%, HBM 4.5% -> barrier-serialized latency. Round-2->3
// gain tracked occupancy exactly, proving the scan (not the match path) was
// the wall. Fix: sort edge ids by bucket once (count/prefix/scatter), then
// stats walks a dense list with no redundant reads and no barriers.
//
// Pipeline:
//   1. count   : LDS histogram of dst>>9 per 1024-block chunk -> counts[b][blk]
//   2. scan    : per-bucket exclusive prefix over blocks (+ totals[b])
//   3. scatter : records[b*CAPB + off] = (dst&511)<<23 | e   (u32, e<2^23)
//   4. stats   : block (part,bucket) walks dense records, gathers scores[e],
//                LDS-accumulates 512x17 tile, plain stores to partials
//   5. coeff   : reduce partials; AB[node] = [A(8)|B(8)] one 64B line
//   6. edge_out: out = A[dst]*x + B[dst]

#define NHEADS  8
#define KSHIFT  9
#define KNODES  512
#define SLOTS   17            // 8 sum + 8 sumsq + 1 count
#define NNODES  100000
#define NB      196           // ceil(100000/512)
#define CBLK    1024          // count/scatter blocks
#define CAPB    20480         // per-bucket capacity (mean 16327, sigma ~127)
#define PARTS_B 4

__global__ __launch_bounds__(256)
void count_kernel(const int* __restrict__ dst, unsigned* __restrict__ counts,
                  int E, int chunk) {
    __shared__ unsigned hist[NB];
    for (int i = threadIdx.x; i < NB; i += 256) hist[i] = 0u;
    __syncthreads();
    const int blk = blockIdx.x;
    const int s0 = blk * chunk;
    const int s1 = min(s0 + chunk, E);
    for (int i = s0 + (int)threadIdx.x * 4; i < s1; i += 256 * 4) {
        if (i + 4 <= s1) {
            int4 d = *reinterpret_cast<const int4*>(dst + i);
            atomicAdd(&hist[(unsigned)d.x >> KSHIFT], 1u);
            atomicAdd(&hist[(unsigned)d.y >> KSHIFT], 1u);
            atomicAdd(&hist[(unsigned)d.z >> KSHIFT], 1u);
            atomicAdd(&hist[(unsigned)d.w >> KSHIFT], 1u);
        } else {
            for (int j = i; j < s1; ++j)
                atomicAdd(&hist[(unsigned)dst[j] >> KSHIFT], 1u);
        }
    }
    __syncthreads();
    for (int b = threadIdx.x; b < NB; b += 256)
        counts[(size_t)b * CBLK + blk] = hist[b];
}

// One block per bucket: exclusive scan of counts[b][0..CBLK) in place.
__global__ __launch_bounds__(256)
void scan_kernel(unsigned* __restrict__ counts, unsigned* __restrict__ totals) {
    __shared__ unsigned sc[256];
    const int b = blockIdx.x;
    const size_t base = (size_t)b * CBLK + (size_t)threadIdx.x * 4;
    uint4 v = *reinterpret_cast<uint4*>(counts + base);
    unsigned s = v.x + v.y + v.z + v.w;
    sc[threadIdx.x] = s;
    __syncthreads();
    for (int off = 1; off < 256; off <<= 1) {
        unsigned t = (threadIdx.x >= (unsigned)off) ? sc[threadIdx.x - off] : 0u;
        __syncthreads();
        sc[threadIdx.x] += t;
        __syncthreads();
    }
    unsigned excl = sc[threadIdx.x] - s;
    uint4 o;
    o.x = excl;
    o.y = excl + v.x;
    o.z = o.y + v.y;
    o.w = o.z + v.z;
    *reinterpret_cast<uint4*>(counts + base) = o;
    if (threadIdx.x == 255) totals[b] = sc[255];
}

__global__ __launch_bounds__(256)
void scatter_kernel(const int* __restrict__ dst, const unsigned* __restrict__ counts,
                    unsigned* __restrict__ records, int E, int chunk) {
    __shared__ unsigned cur[NB];
    const int blk = blockIdx.x;
    for (int b = threadIdx.x; b < NB; b += 256)
        cur[b] = counts[(size_t)b * CBLK + blk];
    __syncthreads();
    const int s0 = blk * chunk;
    const int s1 = min(s0 + chunk, E);
    for (int i = s0 + (int)threadIdx.x; i < s1; i += 256) {
        int d = dst[i];
        unsigned b = (unsigned)d >> KSHIFT;
        unsigned off = atomicAdd(&cur[b], 1u);
        if (off < CAPB)   // statically impossible for uniform dst; guards corruption
            records[(size_t)b * CAPB + off] =
                ((unsigned)(d & (KNODES - 1)) << 23) | (unsigned)i;
    }
}

__global__ __launch_bounds__(256)
void stats_kernel(const unsigned* __restrict__ records,
                  const unsigned* __restrict__ totals,
                  const float* __restrict__ scores,
                  float* __restrict__ partials) {
    __shared__ float st[KNODES * SLOTS];     // 34816 B -> 4 blocks/CU
    const int part = blockIdx.x;
    const int b    = blockIdx.y;
    float4* stv = reinterpret_cast<float4*>(st);
    for (int i = threadIdx.x; i < (KNODES * SLOTS) / 4; i += 256)
        stv[i] = float4{0.f, 0.f, 0.f, 0.f};
    __syncthreads();

    const int cnt = (int)totals[b];
    const int seg = (cnt + PARTS_B - 1) / PARTS_B;
    const int i0 = part * seg;
    const int i1 = min(cnt, i0 + seg);
    const unsigned* rec = records + (size_t)b * CAPB;

    // Dense walk; two edges per iteration for load-level parallelism.
    for (int i = i0 + (int)threadIdx.x; i < i1; i += 512) {
        int j = i + 256;
        unsigned r0 = rec[i];
        unsigned r1 = (j < i1) ? rec[j] : 0u;
        const float4* p0 = reinterpret_cast<const float4*>(
            scores + (size_t)(r0 & 0x7FFFFFu) * NHEADS);
        float4 a0 = p0[0], c0 = p0[1];
        float4 a1, c1;
        if (j < i1) {
            const float4* p1 = reinterpret_cast<const float4*>(
                scores + (size_t)(r1 & 0x7FFFFFu) * NHEADS);
            a1 = p1[0]; c1 = p1[1];
        }
        {
            float* s = st + (int)(r0 >> 23) * SLOTS;   // stride 17: odd
            atomicAdd(s + 0,  a0.x);       atomicAdd(s + 1,  a0.y);
            atomicAdd(s + 2,  a0.z);       atomicAdd(s + 3,  a0.w);
            atomicAdd(s + 4,  c0.x);       atomicAdd(s + 5,  c0.y);
            atomicAdd(s + 6,  c0.z);       atomicAdd(s + 7,  c0.w);
            atomicAdd(s + 8,  a0.x * a0.x); atomicAdd(s + 9,  a0.y * a0.y);
            atomicAdd(s + 10, a0.z * a0.z); atomicAdd(s + 11, a0.w * a0.w);
            atomicAdd(s + 12, c0.x * c0.x); atomicAdd(s + 13, c0.y * c0.y);
            atomicAdd(s + 14, c0.z * c0.z); atomicAdd(s + 15, c0.w * c0.w);
            atomicAdd(s + 16, 1.0f);
        }
        if (j < i1) {
            float* s = st + (int)(r1 >> 23) * SLOTS;
            atomicAdd(s + 0,  a1.x);       atomicAdd(s + 1,  a1.y);
            atomicAdd(s + 2,  a1.z);       atomicAdd(s + 3,  a1.w);
            atomicAdd(s + 4,  c1.x);       atomicAdd(s + 5,  c1.y);
            atomicAdd(s + 6,  c1.z);       atomicAdd(s + 7,  c1.w);
            atomicAdd(s + 8,  a1.x * a1.x); atomicAdd(s + 9,  a1.y * a1.y);
            atomicAdd(s + 10, a1.z * a1.z); atomicAdd(s + 11, a1.w * a1.w);
            atomicAdd(s + 12, c1.x * c1.x); atomicAdd(s + 13, c1.y * c1.y);
            atomicAdd(s + 14, c1.z * c1.z); atomicAdd(s + 15, c1.w * c1.w);
            atomicAdd(s + 16, 1.0f);
        }
    }
    __syncthreads();

    float* out = partials + ((size_t)b * PARTS_B + part) * (KNODES * SLOTS);
    float4* outv = reinterpret_cast<float4*>(out);
    for (int i = threadIdx.x; i < (KNODES * SLOTS) / 4; i += 256)
        outv[i] = stv[i];
}

// AB layout: per node 16 floats = one 64B line: [A(8) | B(8)].
__global__ __launch_bounds__(256)
void coeff_kernel(const float* __restrict__ partials,
                  const float* __restrict__ gain,
                  const float* __restrict__ bias,
                  float* __restrict__ AB, int total) {
    int i = blockIdx.x * 256 + threadIdx.x;
    if (i >= total) return;
    int node = i >> 3, h = i & 7;
    int b = node >> KSHIFT;
    int k = node & (KNODES - 1);
    const float* base =
        partials + (size_t)b * PARTS_B * (KNODES * SLOTS) + (size_t)k * SLOTS;
    float s = 0.f, q = 0.f, c = 0.f;
    #pragma unroll
    for (int p = 0; p < PARTS_B; p++) {
        const float* pp = base + (size_t)p * (KNODES * SLOTS);
        s += pp[h];
        q += pp[8 + h];
        c += pp[16];
    }
    float cm   = fmaxf(c, 1.0f);                 // ref: sums / max(counts,1)
    float mean = s / cm;
    float var  = fmaxf(q - s * mean, 0.0f);      // one-pass variance, clamped
    float inv  = 1.0f / fmaxf(sqrtf(var / cm), 1e-5f);
    float a = gain[h] * inv;
    AB[(size_t)node * 16 + h]     = a;
    AB[(size_t)node * 16 + 8 + h] = fmaf(-a, mean, bias[h]);
}

__global__ __launch_bounds__(256)
void edge_out_kernel(const float* __restrict__ scores,
                     const int* __restrict__ dst,
                     const float* __restrict__ AB,
                     float* __restrict__ out,
                     int num_edges) {
    int e = blockIdx.x * 256 + threadIdx.x;
    if (e >= num_edges) return;
    int d = dst[e];
    const float4* px  = reinterpret_cast<const float4*>(scores + (size_t)e * NHEADS);
    const float4* pab = reinterpret_cast<const float4*>(AB + (size_t)d * 16);
    float4 x0 = px[0], x1 = px[1];
    float4 a0 = pab[0], a1 = pab[1];
    float4 b0 = pab[2], b1 = pab[3];
    float4 o0, o1;
    o0.x = fmaf(a0.x, x0.x, b0.x);
    o0.y = fmaf(a0.y, x0.y, b0.y);
    o0.z = fmaf(a0.z, x0.z, b0.z);
    o0.w = fmaf(a0.w, x0.w, b0.w);
    o1.x = fmaf(a1.x, x1.x, b1.x);
    o1.y = fmaf(a1.y, x1.y, b1.y);
    o1.z = fmaf(a1.z, x1.z, b1.z);
    o1.w = fmaf(a1.w, x1.w, b1.w);
    float4* po = reinterpret_cast<float4*>(out + (size_t)e * NHEADS);
    po[0] = o0;
    po[1] = o1;
}

// ---- global-atomic fallback (only if ws too small / E too large) ----------
__global__ void edge_stats_fallback(const float* __restrict__ scores,
                                    const int* __restrict__ dst,
                                    float* __restrict__ sums,
                                    float* __restrict__ sumsq,
                                    int* __restrict__ counts,
                                    int num_edges) {
    int e = blockIdx.x * blockDim.x + threadIdx.x;
    if (e >= num_edges) return;
    int d = dst[e];
    const float4* p = reinterpret_cast<const float4*>(scores + (size_t)e * NHEADS);
    float4 x0 = p[0], x1 = p[1];
    float* s = sums  + (size_t)d * NHEADS;
    float* q = sumsq + (size_t)d * NHEADS;
    atomicAdd(s + 0, x0.x); atomicAdd(s + 1, x0.y);
    atomicAdd(s + 2, x0.z); atomicAdd(s + 3, x0.w);
    atomicAdd(s + 4, x1.x); atomicAdd(s + 5, x1.y);
    atomicAdd(s + 6, x1.z); atomicAdd(s + 7, x1.w);
    atomicAdd(q + 0, x0.x * x0.x); atomicAdd(q + 1, x0.y * x0.y);
    atomicAdd(q + 2, x0.z * x0.z); atomicAdd(q + 3, x0.w * x0.w);
    atomicAdd(q + 4, x1.x * x1.x); atomicAdd(q + 5, x1.y * x1.y);
    atomicAdd(q + 6, x1.z * x1.z); atomicAdd(q + 7, x1.w * x1.w);
    atomicAdd(counts + d, 1);
}

__global__ void coeff_fallback(const float* __restrict__ sums,
                               const float* __restrict__ sumsq,
                               const int* __restrict__ counts,
                               const float* __restrict__ gain,
                               const float* __restrict__ bias,
                               float* __restrict__ AB, int total) {
    int i = blockIdx.x * blockDim.x + threadIdx.x;
    if (i >= total) return;
    int h = i & (NHEADS - 1);
    int node = i >> 3;
    float cm = fmaxf((float)counts[node], 1.0f);
    float s = sums[i];
    float mean = s / cm;
    float var_sum = fmaxf(sumsq[i] - s * mean, 0.0f);
    float inv = 1.0f / fmaxf(sqrtf(var_sum / cm), 1e-5f);
    float a = gain[h] * inv;
    AB[(size_t)node * 16 + h]     = a;
    AB[(size_t)node * 16 + 8 + h] = fmaf(-a, mean, bias[h]);
}
// ---------------------------------------------------------------------------

extern "C" void kernel_launch(void* const* d_in, const int* in_sizes, int n_in,
                              void* d_out, int out_size, void* d_ws, size_t ws_size,
                              hipStream_t stream) {
    const float* scores = (const float*)d_in[0];
    const float* gain   = (const float*)d_in[1];
    const float* bias   = (const float*)d_in[2];
    const int*   dst    = (const int*)d_in[3];

    const int E  = in_sizes[3];
    const int N  = NNODES;
    const int NH = N * NHEADS;

    // ws layout (256B-aligned sections):
    //   AB       : N*16 f32                     6.40 MB
    //   counts   : NB*CBLK u32                  0.80 MB
    //   totals   : NB u32
    //   records  : NB*CAPB u32                 16.06 MB
    //   partials : NB*PARTS_B*KNODES*SLOTS f32 27.30 MB
    size_t off = 0;
    float* AB = (float*)d_ws;                     off += (size_t)N * 16 * 4;
    off = (off + 255) & ~(size_t)255;
    unsigned* counts = (unsigned*)((char*)d_ws + off); off += (size_t)NB * CBLK * 4;
    off = (off + 255) & ~(size_t)255;
    unsigned* totals = (unsigned*)((char*)d_ws + off); off += (size_t)NB * 4;
    off = (off + 255) & ~(size_t)255;
    unsigned* records = (unsigned*)((char*)d_ws + off); off += (size_t)NB * CAPB * 4;
    off = (off + 255) & ~(size_t)255;
    float* partials = (float*)((char*)d_ws + off);
    off += (size_t)NB * PARTS_B * KNODES * SLOTS * 4;

    const int B = 256;
    const bool fits = (off <= ws_size) && (E < (1 << 23)) &&
                      ((size_t)E <= (size_t)NB * CAPB);

    if (fits) {
        int chunk = (((E + CBLK - 1) / CBLK) + 3) & ~3;
        count_kernel<<<CBLK, B, 0, stream>>>(dst, counts, E, chunk);
        scan_kernel<<<NB, B, 0, stream>>>(counts, totals);
        scatter_kernel<<<CBLK, B, 0, stream>>>(dst, counts, records, E, chunk);
        dim3 gs(PARTS_B, NB);
        stats_kernel<<<gs, B, 0, stream>>>(records, totals, scores, partials);
        coeff_kernel<<<(NH + B - 1) / B, B, 0, stream>>>(partials, gain, bias, AB, NH);
        edge_out_kernel<<<(E + B - 1) / B, B, 0, stream>>>(scores, dst, AB, (float*)d_out, E);
    } else {
        float* sums  = (float*)((char*)d_ws + (size_t)N * 16 * 4);
        float* sumsq = sums + NH;
        int*   cnts  = (int*)(sumsq + NH);
        hipMemsetAsync(sums, 0,
                       (size_t)(2 * NH) * sizeof(float) + (size_t)N * sizeof(int), stream);
        int blocks_e = (E + B - 1) / B;
        edge_stats_fallback<<<blocks_e, B, 0, stream>>>(scores, dst, sums, sumsq, cnts, E);
        coeff_fallback<<<(NH + B - 1) / B, B, 0, stream>>>(sums, sumsq, cnts, gain, bias, AB, NH);
        edge_out_kernel<<<blocks_e, B, 0, stream>>>(scores, dst, AB, (float*)d_out, E);
    }
}